// Round 8
// baseline (101.395 us; speedup 1.0000x reference)
//
#include <hip/hip_runtime.h>
#include <stdint.h>
#include <math.h>

// Negative L1 cdist: out[n,m] = -sum_d |x[n,d] - w[m,d]|
// N=8192, M=1024, D=64, fp32 in/out.
//
// R14 post-mortem: VGPR=28 (< acc16+w16), FETCH 8.5MB -> even a 16-float
// chunk gets re-loaded per row. Root cause identified: const/__restrict__
// global loads are "trivially rematerializable" in LLVM -> the RA re-executes
// them per use to cut pressure. No pure-C shape wins (R11-R14 = 4 losses).
// R15: the load itself becomes asm volatile (cannot be duplicated / sunk /
// remat'd; direct "=&v" outputs are the SUPPORTED form, unlike R12's tied
// indirect). RA must keep the 16 floats in VGPRs (~55 live, no spill reason).
//   - x: block-uniform s_load/SGPR broadcast (R13/R14-proven; SGPR = free
//     VALU operand, exactly 1 SGPR src per v_sub_f32 -- legal).
//   - occupancy: (256,6) = 6 waves/SIMD (85-reg budget vs ~55 used) to
//     cover per-row SMEM latency (R14: VALUBusy 57% @ 4 waves).
//   - body per (chunk,row): 16 v_sub + 16 v_add(acc,acc,|.|) + 4 tree
//     -> 37k cyc/SIMD = 15.4us issue floor; expect 19-25us.

constexpr int Nn = 8192, Mm = 1024, Dd = 64;
constexpr int NR = 16;                        // n-rows per block

__global__ __launch_bounds__(256, 6) void cdist_l1_f32_kernel(
    const float* __restrict__ x, const float* __restrict__ w,
    float* __restrict__ out)
{
    const int t   = threadIdx.x;
    const int bid = blockIdx.x;
    const int mg  = bid & 3;                  // m-group: 256 columns each
    const int n0  = (bid >> 2) * NR;
    const int m   = mg * 256 + t;

    float acc[NR];
#pragma unroll
    for (int j = 0; j < NR; ++j) acc[j] = 0.f;

    const float* wrow = w + (size_t)m * Dd;
    const float* xb   = x + (size_t)n0 * Dd;

#pragma unroll 1
    for (int dc = 0; dc < 4; ++dc) {
        // Volatile asm loads: the RA cannot rematerialize/sink these ->
        // the 16 floats STAY in VGPRs across the whole j-loop.
        float4 w0, w1, w2, w3;
        {
            const float* wa = wrow + dc * 16;
            asm volatile(
                "global_load_dwordx4 %0, %4, off\n\t"
                "global_load_dwordx4 %1, %4, off offset:16\n\t"
                "global_load_dwordx4 %2, %4, off offset:32\n\t"
                "global_load_dwordx4 %3, %4, off offset:48\n\t"
                "s_waitcnt vmcnt(0)"
                : "=&v"(w0), "=&v"(w1), "=&v"(w2), "=&v"(w3)
                : "v"(wa));
        }
#pragma unroll
        for (int j = 0; j < NR; ++j) {
            // block-uniform address -> s_load into SGPRs (free VALU src)
            const float4* xr = (const float4*)(xb + j * Dd + dc * 16);
            const float4 x0 = xr[0], x1 = xr[1], x2 = xr[2], x3 = xr[3];
            // 4 independent chains per row; body = sub + add(|.|) only
            float a = 0.f, b = 0.f, c = 0.f, d = 0.f;
            a += __builtin_fabsf(x0.x - w0.x); b += __builtin_fabsf(x0.y - w0.y);
            c += __builtin_fabsf(x0.z - w0.z); d += __builtin_fabsf(x0.w - w0.w);
            a += __builtin_fabsf(x1.x - w1.x); b += __builtin_fabsf(x1.y - w1.y);
            c += __builtin_fabsf(x1.z - w1.z); d += __builtin_fabsf(x1.w - w1.w);
            a += __builtin_fabsf(x2.x - w2.x); b += __builtin_fabsf(x2.y - w2.y);
            c += __builtin_fabsf(x2.z - w2.z); d += __builtin_fabsf(x2.w - w2.w);
            a += __builtin_fabsf(x3.x - w3.x); b += __builtin_fabsf(x3.y - w3.y);
            c += __builtin_fabsf(x3.z - w3.z); d += __builtin_fabsf(x3.w - w3.w);
            acc[j] += (a + b) + (c + d);      // static index (fully unrolled)
        }
    }

    // coalesced 256 B/wave segments; nontemporal: out is never re-read
    float* o = out + (size_t)n0 * Mm + m;
#pragma unroll
    for (int j = 0; j < NR; ++j)
        __builtin_nontemporal_store(-acc[j], o + (size_t)j * Mm);
}

extern "C" void kernel_launch(void* const* d_in, const int* in_sizes, int n_in,
                              void* d_out, int out_size, void* d_ws, size_t ws_size,
                              hipStream_t stream) {
    (void)in_sizes; (void)n_in; (void)out_size; (void)d_ws; (void)ws_size;
    const float* x = (const float*)d_in[0];   // [8192, 64] fp32
    const float* w = (const float*)d_in[1];   // [1024, 64] fp32
    float* out = (float*)d_out;               // [8192, 1024] fp32

    // (8192/16) n-blocks x 4 m-groups = 2048 blocks = 8 blocks/CU
    cdist_l1_f32_kernel<<<dim3((Nn / NR) * 4), dim3(256), 0, stream>>>(
        x, w, out);
}